// Round 4
// baseline (117.979 us; speedup 1.0000x reference)
//
#include <hip/hip_runtime.h>
#include <hip/hip_bf16.h>
#include <stdint.h>

// cheb_conv_with_Att_static: out[b,t,v,c] = relu( sum_{k,f} theta[k,f,c] *
//     sum_u cheb[k,u,v]*Att[b,u,v]*x[b,t,u,f] )
// B=8 T=12 V=2048 F=16 K=3 C=64
#define B_  8
#define T_  12
#define V_  2048
#define F_  16
#define K_  3
#define C_  64
#define N_  192   // T*F

typedef _Float16 f16;
typedef _Float16 half4v __attribute__((ext_vector_type(4)));
typedef _Float16 half8v __attribute__((ext_vector_type(8)));
typedef float    f32x4  __attribute__((ext_vector_type(4)));
typedef float    f32x16 __attribute__((ext_vector_type(16)));
typedef unsigned int u32;

// ---------------------------------------------------------------------------
// Kernel 1a: XT[b][n=t*16+f][u] = (f16) x[b][t][u][f]   (u becomes contiguous)
// ---------------------------------------------------------------------------
__global__ __launch_bounds__(256) void prep_xt(const float* __restrict__ x,
                                               f16* __restrict__ XT) {
  int bid = blockIdx.x;
  int bt = bid >> 2, uc = bid & 3;
  int b = bt / T_, t = bt % T_;
  __shared__ float tile[64][17];
  int r  = threadIdx.x >> 2, fq = threadIdx.x & 3;   // load mapping
  int f  = threadIdx.x >> 4, uq = threadIdx.x & 15;  // store mapping
  for (int u0 = uc * 512; u0 < uc * 512 + 512; u0 += 64) {
    f32x4 v = *(const f32x4*)(x + ((size_t)(b * T_ + t) * V_ + u0 + r) * F_ + fq * 4);
    tile[r][fq * 4 + 0] = v[0];
    tile[r][fq * 4 + 1] = v[1];
    tile[r][fq * 4 + 2] = v[2];
    tile[r][fq * 4 + 3] = v[3];
    __syncthreads();
    half4v h;
    h[0] = (f16)tile[uq * 4 + 0][f];
    h[1] = (f16)tile[uq * 4 + 1][f];
    h[2] = (f16)tile[uq * 4 + 2][f];
    h[3] = (f16)tile[uq * 4 + 3][f];
    *(half4v*)(XT + (size_t)(b * N_ + t * F_ + f) * V_ + u0 + uq * 4) = h;
    __syncthreads();
  }
}

// ---------------------------------------------------------------------------
// Kernel 1b: cheb16 = (f16) cheb   (same [k][u][v] layout, halves gemm stream
// and halves A-staging register footprint in the gemm)
// ---------------------------------------------------------------------------
__global__ __launch_bounds__(256) void prep_cheb(const float* __restrict__ c,
                                                 f16* __restrict__ c16) {
  size_t i = ((size_t)blockIdx.x * 256 + threadIdx.x) * 4;
  f32x4 v = *(const f32x4*)(c + i);
  half4v h;
  h[0] = (f16)v[0]; h[1] = (f16)v[1]; h[2] = (f16)v[2]; h[3] = (f16)v[3];
  *(half4v*)(c16 + i) = h;
}

// ---------------------------------------------------------------------------
// Kernel 2 (k-fused, u-split): per (b,vt,uh): for all 3 k,
//   rhs[b][t][v][uh*48+k*16+f] = sum_{u in half} (cheb[k,u,v]*Att[b,u,v]) * XT[b,n,u]
// BM=64 BN=192 BK=64, 4 waves (2x2), wave tile 32x96, 32x32x16 f16 MFMA.
// Round-4: regs under the 256 cliff (2 waves/SIMD) + B double-buffer so the
// glds vmcnt drain at barrier-1 is hidden under the compute phase.
//   per step: issue A-loads(t+1) -> regs; glds B(t+1) -> Bb[alt];
//             COMPUTE(t) (Ab, Bb[cur]); products(t+1) -> pk;
//             barrier (vmcnt drain overlapped w/ compute);
//             writeA(pk) -> Ab; barrier (lgkm only).
// LDS 72KB (A 24 + B 2x24): 2 blocks/CU.  XCD: b = bid&7 (XT[b] per-XCD L2).
// ---------------------------------------------------------------------------
#define COMPUTE_KS(ks, BPTR)                                                    \
  {                                                                             \
    const int ku2 = (ks) * 32 + (lane >> 5) * 16;                               \
    half8v bfr0 = *(const half8v*)((BPTR) + nrowA[0] * 128 + (ku2 ^ bkeyA[0])); \
    half8v bfr1 = *(const half8v*)((BPTR) + nrowA[1] * 128 + (ku2 ^ bkeyA[1])); \
    half8v bfr2 = *(const half8v*)((BPTR) + nrowA[2] * 128 + (ku2 ^ bkeyA[2])); \
    __builtin_amdgcn_s_setprio(1);                                              \
    _Pragma("unroll")                                                           \
    for (int k = 0; k < 3; ++k) {                                               \
      half8v a = *(const half8v*)(Ab + k * 8192 + vrow * 128 + (ku2 ^ akey));   \
      acc[k][0] = __builtin_amdgcn_mfma_f32_32x32x16_f16(a, bfr0, acc[k][0], 0, 0, 0); \
      acc[k][1] = __builtin_amdgcn_mfma_f32_32x32x16_f16(a, bfr1, acc[k][1], 0, 0, 0); \
      acc[k][2] = __builtin_amdgcn_mfma_f32_32x32x16_f16(a, bfr2, acc[k][2], 0, 0, 0); \
    }                                                                           \
    __builtin_amdgcn_s_setprio(0);                                              \
  }

template<int UH, bool F16C>
__global__ __launch_bounds__(256, 2) void gemm_fused(const float* __restrict__ Att,
                                                     const void* __restrict__ chebp,
                                                     const f16* __restrict__ XT,
                                                     f16* __restrict__ rhs) {
  constexpr int NSTEP = (V_ / UH) / 64;
  const int bid = blockIdx.x;
  const int b  = bid & 7;             // XCD co-location on XT[b]
  const int r2 = bid >> 3;            // 0 .. 32*UH-1
  const int vt = r2 / UH, uh = r2 % UH;
  const int vbase = vt * 64;
  const size_t ubase = (size_t)uh * (V_ / UH);

  __shared__ char smem[73728];        // A 24KB | B0 24KB | B1 24KB
  char* Ab = smem;
  char* Bbuf0 = smem + 24576;
  char* Bbuf1 = smem + 49152;

  const int tid = threadIdx.x;
  const int wave = tid >> 6, lane = tid & 63;
  const int wm = wave >> 1, wn = wave & 1;
  const int vsub = (tid & 15) * 4, usub = (tid >> 4) * 4;

  const float* attb   = Att + (size_t)b * V_ * V_ + vbase + vsub + (size_t)usub * V_;
  const f16*   cb16   = (const f16*)chebp + vbase + vsub + (size_t)usub * V_;
  const float* cbf    = (const float*)chebp + vbase + vsub + (size_t)usub * V_;
  const f16*   xtb    = XT + (size_t)b * N_ * V_;

  f32x16 acc[3][3];
#pragma unroll
  for (int k = 0; k < 3; ++k)
#pragma unroll
    for (int nf = 0; nf < 3; ++nf) acc[k][nf] = 0;

  const int vrow = wm * 32 + (lane & 31);
  const int akey = ((vrow >> 2) & 7) << 4;
  int nrowA[3], bkeyA[3];
#pragma unroll
  for (int nf = 0; nf < 3; ++nf) {
    nrowA[nf] = wn * 96 + nf * 32 + (lane & 31);
    bkeyA[nf] = (nrowA[nf] & 7) << 4;
  }
  const int wkey = (tid & 7) << 4;            // ((vsub+j)>>2 & 7)<<4 for j<4
  const int gl_c = (lane & 7) ^ (lane >> 3);  // pre-swizzled src chunk

  f32x4  pa[4];
  half4v cv16[3][4];
  f32x4  cvf[3][4];

  auto stageB = [&](size_t u, char* Bb) {
#pragma unroll
    for (int e = 0; e < 6; ++e) {
      int slot = wave * 6 + e;
      int n = slot * 8 + (lane >> 3);
      const f16* src = xtb + (size_t)n * V_ + u + gl_c * 8;
      __builtin_amdgcn_global_load_lds((const __attribute__((address_space(1))) u32*)src,
                                       (__attribute__((address_space(3))) u32*)(Bb + slot * 1024),
                                       16, 0, 0);
    }
  };
  auto issueA = [&](size_t u) {
#pragma unroll
    for (int i = 0; i < 4; ++i) pa[i] = *(const f32x4*)(attb + (u + i) * V_);
    if constexpr (F16C) {
#pragma unroll
      for (int k = 0; k < 3; ++k)
#pragma unroll
        for (int i = 0; i < 4; ++i)
          cv16[k][i] = *(const half4v*)(cb16 + (size_t)k * V_ * V_ + (u + i) * V_);
    } else {
#pragma unroll
      for (int k = 0; k < 3; ++k)
#pragma unroll
        for (int i = 0; i < 4; ++i)
          cvf[k][i] = *(const f32x4*)(cbf + (size_t)k * V_ * V_ + (u + i) * V_);
    }
  };
  auto makePk = [&](half4v pk[3][4]) {
    if constexpr (F16C) {
      half4v a16[4];
#pragma unroll
      for (int i = 0; i < 4; ++i) {
        a16[i][0] = (f16)pa[i][0]; a16[i][1] = (f16)pa[i][1];
        a16[i][2] = (f16)pa[i][2]; a16[i][3] = (f16)pa[i][3];
      }
#pragma unroll
      for (int k = 0; k < 3; ++k)
#pragma unroll
        for (int j = 0; j < 4; ++j) {
          half4v h;
          h[0] = cv16[k][0][j] * a16[0][j]; h[1] = cv16[k][1][j] * a16[1][j];
          h[2] = cv16[k][2][j] * a16[2][j]; h[3] = cv16[k][3][j] * a16[3][j];
          pk[k][j] = h;
        }
    } else {
#pragma unroll
      for (int k = 0; k < 3; ++k)
#pragma unroll
        for (int j = 0; j < 4; ++j) {
          half4v h;
          h[0] = (f16)(cvf[k][0][j] * pa[0][j]); h[1] = (f16)(cvf[k][1][j] * pa[1][j]);
          h[2] = (f16)(cvf[k][2][j] * pa[2][j]); h[3] = (f16)(cvf[k][3][j] * pa[3][j]);
          pk[k][j] = h;
        }
    }
  };
  auto writeA = [&](half4v pk[3][4]) {
#pragma unroll
    for (int k = 0; k < 3; ++k)
#pragma unroll
      for (int j = 0; j < 4; ++j)
        *(half4v*)(Ab + k * 8192 + (vsub + j) * 128 + ((usub * 2) ^ wkey)) = pk[k][j];
  };

  // ---- prologue ----
  issueA(ubase);
  stageB(ubase, Bbuf0);
  {
    half4v pk[3][4];
    makePk(pk);
    writeA(pk);
  }
  __syncthreads();

  for (int t = 0; t < NSTEP; ++t) {
    char* Bc = (t & 1) ? Bbuf1 : Bbuf0;
    char* Bn = (t & 1) ? Bbuf0 : Bbuf1;
    const bool pref = (t + 1) < NSTEP;
    const size_t unext = ubase + (size_t)(t + 1) * 64;

    if (pref) {
      issueA(unext);          // A-loads first (waitable at vmcnt(6))
      stageB(unext, Bn);      // glds fly across the compute phase
    }

    COMPUTE_KS(0, Bc)
    COMPUTE_KS(1, Bc)
    COMPUTE_KS(2, Bc)
    COMPUTE_KS(3, Bc)

    half4v pk[3][4];
    if (pref) makePk(pk);
    __syncthreads();          // vmcnt drain: glds had full compute in flight
    if (pref) writeA(pk);
    __syncthreads();          // lgkm-only drain (no outstanding vmem)
  }

  // ---- epilogue: scatter acc -> rhs[b][t][v][uh*48 + k*16 + f] (f16) ----
#pragma unroll
  for (int nf = 0; nf < 3; ++nf) {
    int n = wn * 96 + nf * 32 + (lane & 31);
    int tt = n >> 4, fi = n & 15;
#pragma unroll
    for (int k = 0; k < 3; ++k) {
#pragma unroll
      for (int r = 0; r < 16; ++r) {
        int v = vbase + wm * 32 + (r & 3) + 8 * (r >> 2) + 4 * (lane >> 5);
        rhs[((size_t)(b * T_ + tt) * V_ + v) * (48 * UH) + uh * 48 + k * 16 + fi] =
            (f16)acc[k][nf][r];
      }
    }
  }
}
#undef COMPUTE_KS

// ---------------------------------------------------------------------------
// Kernel 3: out[row, c] = relu( sum_{s} rhs[row][s*16+..] * theta[(s%3)*16+..][c] )
// ---------------------------------------------------------------------------
template<int UH>
__global__ __launch_bounds__(256) void epi(const f16* __restrict__ rhs,
                                           const float* __restrict__ theta,
                                           float* __restrict__ out) {
  int wave = threadIdx.x >> 6, lane = threadIdx.x & 63;
  int row0 = blockIdx.x * 128 + wave * 32;
  int cl = lane & 31, kh = (lane >> 5) * 8;

  half8v bf[2][3];
#pragma unroll
  for (int nf = 0; nf < 2; ++nf)
#pragma unroll
    for (int ks = 0; ks < 3; ++ks) {
      half8v hb;
#pragma unroll
      for (int j = 0; j < 8; ++j)
        hb[j] = (f16)theta[(size_t)(ks * 16 + kh + j) * C_ + nf * 32 + cl];
      bf[nf][ks] = hb;
    }

  f32x16 acc0 = 0, acc1 = 0;
#pragma unroll
  for (int s = 0; s < 3 * UH; ++s) {
    half8v a = *(const half8v*)(rhs + (size_t)(row0 + cl) * (48 * UH) + s * 16 + kh);
    acc0 = __builtin_amdgcn_mfma_f32_32x32x16_f16(a, bf[0][s % 3], acc0, 0, 0, 0);
    acc1 = __builtin_amdgcn_mfma_f32_32x32x16_f16(a, bf[1][s % 3], acc1, 0, 0, 0);
  }
#pragma unroll
  for (int r = 0; r < 16; ++r) {
    int row = row0 + (r & 3) + 8 * (r >> 2) + 4 * (lane >> 5);
    out[(size_t)row * C_ + cl]      = fmaxf(acc0[r], 0.f);
    out[(size_t)row * C_ + 32 + cl] = fmaxf(acc1[r], 0.f);
  }
}

// ---------------------------------------------------------------------------
extern "C" void kernel_launch(void* const* d_in, const int* in_sizes, int n_in,
                              void* d_out, int out_size, void* d_ws, size_t ws_size,
                              hipStream_t stream) {
  const float* x     = (const float*)d_in[0];   // (8,12,2048,16)
  const float* Att   = (const float*)d_in[1];   // (8,2048,2048)
  const float* cheb  = (const float*)d_in[2];   // (3,2048,2048)
  const float* theta = (const float*)d_in[3];   // (3,16,64)
  float* out = (float*)d_out;                   // (8,12,2048,64) fp32

  const size_t xtB   = (size_t)B_ * N_ * V_ * sizeof(f16);        // 6.29 MB
  const size_t rhs2B = (size_t)B_ * T_ * V_ * 96 * sizeof(f16);   // 37.7 MB
  const size_t rhs1B = rhs2B / 2;                                 // 18.9 MB
  const size_t chB   = (size_t)K_ * V_ * V_ * sizeof(f16);        // 25.2 MB

  f16* XT = (f16*)d_ws;
  prep_xt<<<B_ * T_ * 4, 256, 0, stream>>>(x, XT);

  if (ws_size >= xtB + rhs2B + chB) {
    f16* rhs = (f16*)((char*)d_ws + xtB);
    f16* c16 = (f16*)((char*)d_ws + xtB + rhs2B);
    prep_cheb<<<(K_ * V_ * V_) / 1024, 256, 0, stream>>>(cheb, c16);
    gemm_fused<2, true><<<B_ * 32 * 2, 256, 0, stream>>>(Att, c16, XT, rhs);
    epi<2><<<(B_ * T_ * V_) / 128, 256, 0, stream>>>(rhs, theta, out);
  } else if (ws_size >= xtB + rhs1B + chB) {
    f16* rhs = (f16*)((char*)d_ws + xtB);
    f16* c16 = (f16*)((char*)d_ws + xtB + rhs1B);
    prep_cheb<<<(K_ * V_ * V_) / 1024, 256, 0, stream>>>(cheb, c16);
    gemm_fused<1, true><<<B_ * 32, 256, 0, stream>>>(Att, c16, XT, rhs);
    epi<1><<<(B_ * T_ * V_) / 128, 256, 0, stream>>>(rhs, theta, out);
  } else {
    f16* rhs = (f16*)((char*)d_ws + xtB);
    gemm_fused<1, false><<<B_ * 32, 256, 0, stream>>>(Att, cheb, XT, rhs);
    epi<1><<<(B_ * T_ * V_) / 128, 256, 0, stream>>>(rhs, theta, out);
  }
}